// Round 1
// baseline (353.916 us; speedup 1.0000x reference)
//
#include <hip/hip_runtime.h>

// Problem constants (from reference): VOCAB=100000, EMB=300, B=2048, L=200, H=128, OUT=20
#define BB   2048
#define LL   200
#define EMB  300
#define HH   128
#define OUTD 20

// One block per sample. 256 threads:
//   phase 1: gather-sum over L rows of the embedding table (memory-bound).
//            thread t owns channel t; threads 0..43 also own channel 256+t.
//   phase 2: MLP. rep in LDS (broadcast reads), W1 columns coalesced across threads.
__global__ __launch_bounds__(256) void fused_dnn(
    const int*   __restrict__ x,        // [B, L]
    const int*   __restrict__ lengths,  // [B]
    const float* __restrict__ table,    // [VOCAB, EMB]
    const float* __restrict__ W1,       // [EMB, H]
    const float* __restrict__ b1,       // [H]
    const float* __restrict__ W2,       // [H, OUT]
    const float* __restrict__ b2,       // [OUT]
    float*       __restrict__ out)      // [B, OUT]
{
    __shared__ int   idx_s[LL];
    __shared__ float rep_s[EMB];
    __shared__ float h_s[HH];

    const int b = blockIdx.x;
    const int t = threadIdx.x;

    // stage this sample's indices
    if (t < LL) idx_s[t] = x[b * LL + t];
    __syncthreads();

    // gather-sum over the full sequence (reference sums full L, divides by length)
    float acc0 = 0.0f, acc1 = 0.0f;
    const bool has2 = (t < (EMB - 256));   // t < 44
    #pragma unroll 4
    for (int l = 0; l < LL; ++l) {
        const float* row = table + (size_t)idx_s[l] * EMB;
        acc0 += row[t];
        if (has2) acc1 += row[256 + t];
    }

    const float inv_len = 1.0f / (float)lengths[b];
    rep_s[t] = acc0 * inv_len;
    if (has2) rep_s[256 + t] = acc1 * inv_len;
    __syncthreads();

    // h = relu(rep @ W1 + b1)   (threads 0..127; W1[k*H + t] coalesced across t)
    if (t < HH) {
        float hacc = b1[t];
        #pragma unroll 4
        for (int k = 0; k < EMB; ++k)
            hacc = fmaf(rep_s[k], W1[k * HH + t], hacc);
        h_s[t] = fmaxf(hacc, 0.0f);
    }
    __syncthreads();

    // logits = h @ W2 + b2      (threads 0..19)
    if (t < OUTD) {
        float oacc = b2[t];
        #pragma unroll
        for (int k = 0; k < HH; ++k)
            oacc = fmaf(h_s[k], W2[k * OUTD + t], oacc);
        out[b * OUTD + t] = oacc;
    }
}

extern "C" void kernel_launch(void* const* d_in, const int* in_sizes, int n_in,
                              void* d_out, int out_size, void* d_ws, size_t ws_size,
                              hipStream_t stream) {
    const int*   x       = (const int*)  d_in[0];
    const int*   lengths = (const int*)  d_in[1];
    const float* table   = (const float*)d_in[2];
    const float* W1      = (const float*)d_in[3];
    const float* b1      = (const float*)d_in[4];
    const float* W2      = (const float*)d_in[5];
    const float* b2      = (const float*)d_in[6];
    float*       out     = (float*)d_out;

    fused_dnn<<<BB, 256, 0, stream>>>(x, lengths, table, W1, b1, W2, b2, out);
}

// Round 2
// 252.101 us; speedup vs baseline: 1.4039x; 1.4039x over previous
//
#include <hip/hip_runtime.h>

// Problem constants: VOCAB=100000, EMB=300, B=2048, L=200, H=128, OUT=20
#define BB   2048
#define LL   200
#define EMB  300
#define HH   128
#define OUTD 20

// One block per sample, 256 threads = 4 waves.
// Phase 1 (gather): each wave owns rows l = w, w+4, ... (50 rows). Within a row
//   (300 floats = 75 float4), lanes 0..63 load float4 #lane, lanes 0..10 load
//   float4 #(64+lane). 16B/lane vectorized → 4x bytes/instr vs scalar.
// Phase 2: cross-wave reduction in LDS, then MLP with split-k W1 GEMV.
__global__ __launch_bounds__(256) void fused_dnn(
    const int*   __restrict__ x,        // [B, L]
    const int*   __restrict__ lengths,  // [B]
    const float* __restrict__ table,    // [VOCAB, EMB]
    const float* __restrict__ W1,       // [EMB, H]
    const float* __restrict__ b1,       // [H]
    const float* __restrict__ W2,       // [H, OUT]
    const float* __restrict__ b2,       // [OUT]
    float*       __restrict__ out)      // [B, OUT]
{
    __shared__ int    idx_s[LL];
    __shared__ float4 part_s[4][76];    // [wave][304 floats] (75 float4 used + pad)
    __shared__ float  rep_s[EMB];
    __shared__ float  h_part[2][HH];
    __shared__ float  h_s[HH];

    const int b    = blockIdx.x;
    const int t    = threadIdx.x;
    const int w    = t >> 6;            // wave 0..3
    const int lane = t & 63;

    if (t < LL) idx_s[t] = x[b * LL + t];
    __syncthreads();

    float4 acc_a = make_float4(0.f, 0.f, 0.f, 0.f);
    float4 acc_b = make_float4(0.f, 0.f, 0.f, 0.f);
    const bool hasb = (lane < (EMB / 4 - 64));   // lane < 11

    #pragma unroll 2
    for (int l = w; l < LL; l += 4) {
        const float4* row = (const float4*)(table + (size_t)idx_s[l] * EMB);
        float4 va = row[lane];
        acc_a.x += va.x; acc_a.y += va.y; acc_a.z += va.z; acc_a.w += va.w;
        if (hasb) {
            float4 vb = row[64 + lane];
            acc_b.x += vb.x; acc_b.y += vb.y; acc_b.z += vb.z; acc_b.w += vb.w;
        }
    }

    part_s[w][lane] = acc_a;
    if (hasb) part_s[w][64 + lane] = acc_b;
    __syncthreads();

    // cross-wave reduce + scale; rep_s[0..299]
    const float inv_len = 1.0f / (float)lengths[b];
    const float* ps = (const float*)part_s;      // [4][304] floats
    {
        float s = ps[t] + ps[304 + t] + ps[608 + t] + ps[912 + t];
        rep_s[t] = s * inv_len;                  // t covers 0..255
    }
    if (t < (EMB - 256)) {                       // t < 44 → channels 256..299
        int c = 256 + t;
        float s = ps[c] + ps[304 + c] + ps[608 + c] + ps[912 + c];
        rep_s[c] = s * inv_len;
    }
    __syncthreads();

    // h = relu(rep @ W1 + b1), split-k: half 0 does k=0..149, half 1 k=150..299
    {
        const int half = t >> 7;                 // 0 or 1
        const int col  = t & 127;
        float hacc = (half == 0) ? b1[col] : 0.0f;
        const int k0 = half * (EMB / 2);
        #pragma unroll 5
        for (int k = k0; k < k0 + EMB / 2; ++k)
            hacc = fmaf(rep_s[k], W1[k * HH + col], hacc);
        h_part[half][col] = hacc;
    }
    __syncthreads();
    if (t < HH)
        h_s[t] = fmaxf(h_part[0][t] + h_part[1][t], 0.0f);
    __syncthreads();

    // logits = h @ W2 + b2
    if (t < OUTD) {
        float oacc = b2[t];
        #pragma unroll
        for (int k = 0; k < HH; ++k)
            oacc = fmaf(h_s[k], W2[k * OUTD + t], oacc);
        out[b * OUTD + t] = oacc;
    }
}

extern "C" void kernel_launch(void* const* d_in, const int* in_sizes, int n_in,
                              void* d_out, int out_size, void* d_ws, size_t ws_size,
                              hipStream_t stream) {
    const int*   x       = (const int*)  d_in[0];
    const int*   lengths = (const int*)  d_in[1];
    const float* table   = (const float*)d_in[2];
    const float* W1      = (const float*)d_in[3];
    const float* b1      = (const float*)d_in[4];
    const float* W2      = (const float*)d_in[5];
    const float* b2      = (const float*)d_in[6];
    float*       out     = (float*)d_out;

    fused_dnn<<<BB, 256, 0, stream>>>(x, lengths, table, W1, b1, W2, b2, out);
}